// Round 15
// baseline (34.829 us; speedup 1.0000x reference)
//
#include <hip/hip_runtime.h>
#include <hip/hip_bf16.h>

#define NBINS 32
#define CHUNK 128           // voxels per chunk per block
#define NROWS 34            // rows 1..32 = bins 0..31; rows 0/33 = clamp garbage
#define STR 136             // halfs per row; 272B stride, 16B-aligned rows, conflict-free b128 reads
#define TILE_HALVES (NROWS * STR)        // 4624 halfs = 9248 B
#define BUF_HALVES (2 * TILE_HALVES)     // A+B tiles per ping-pong buffer
#define NTHREADS 256
#define NVOX 884736         // 96^3 = 6912 * 128
#define BPB 512             // grid (512,2) = 1024 blocks = 4/CU (37 KB LDS)
#define NSLOTS 16

typedef __attribute__((ext_vector_type(8))) _Float16 half8;
typedef __attribute__((ext_vector_type(16))) float f32x16;
typedef __attribute__((ext_vector_type(4))) int i32x4;

// Parzen 6-tap window — BIT-IDENTICAL math to the validated R4-R14 kernels.
__device__ __forceinline__ void compute_w(float x, int& kb, _Float16* wq) {
    float tt = x * 31.0f;
    float kf = rintf(tt);
    int ki = (int)kf;
    float u = tt - kf;               // [-0.5, 0.5]
    kb = ki - 3 + (u > 0.0f ? 1 : 0);
    float w[6];
    float s = 0.0f;
#pragma unroll
    for (int o = 0; o < 6; ++o) {
        int b = kb + o;
        float d = tt - (float)b;
        float e = __expf(-2.0f * d * d);
        e = ((unsigned)b < NBINS) ? e : 0.0f;
        w[o] = e;
        s += e;
    }
    float rinv = 1.0f / s;
#pragma unroll
    for (int o = 0; o < 6; ++o) wq[o] = (_Float16)(w[o] * rinv);
}

__device__ __forceinline__ void zero6(_Float16* __restrict__ L, int col, int kb) {
#pragma unroll
    for (int o = 0; o < 6; ++o) {
        int r = min(max(kb + o, -1), 32) + 1;
        L[r * STR + col] = (_Float16)0.0f;
    }
}
__device__ __forceinline__ void scatter6(_Float16* __restrict__ L, int col, int kb,
                                         const _Float16* wq) {
#pragma unroll
    for (int o = 0; o < 6; ++o) {
        int r = min(max(kb + o, -1), 32) + 1;
        L[r * STR + col] = wq[o];
    }
}

__device__ __forceinline__ int flg_load(const int* f) {
    return __hip_atomic_load(f, __ATOMIC_ACQUIRE, __HIP_MEMORY_SCOPE_WORKGROUP);
}
__device__ __forceinline__ void flg_store(int* f, int v) {
    __hip_atomic_store(f, v, __ATOMIC_RELEASE, __HIP_MEMORY_SCOPE_WORKGROUP);
}

__global__ __launch_bounds__(NTHREADS, 4)
void mi_hist_kernel(const float* __restrict__ pred, const float* __restrict__ targ,
                    float* __restrict__ hist /* [NSLOTS][2][32][32] */) {
    // ping-pong buffers, each = A tile + B tile. Producers (waves 0,1) fill;
    // consumers (waves 2,3) MFMA. Sync: LDS epoch flags, NO block barriers in loop.
    __shared__ __attribute__((aligned(16))) _Float16 smem[2 * BUF_HALVES];   // 36992 B
    __shared__ int flg[8];   // [q*2+w]   = pflag: producer w filled buffer q, epoch c+1
                             // [4+q*2+i] = cflag: consumer i done reading buffer q, epoch c+1

    const int tid = threadIdx.x;
    const int bx = blockIdx.x;
    const int batch = blockIdx.y;
    const int wid = tid >> 6;
    const int lane = tid & 63;
    // 6912 slabs/batch = 512*13 + 256 -> bx<256 run 14 chunks, rest 13 (block-uniform)
    const int nchunks = (bx < 256) ? 14 : 13;

    // prologue: zero both buffers + flags; the ONLY barrier before the epilogue
    {
        i32x4 z = {0, 0, 0, 0};
        i32x4* zp = (i32x4*)smem;
        for (int i = tid; i < (2 * BUF_HALVES) / 8; i += NTHREADS) zp[i] = z;
    }
    if (tid < 8) flg[tid] = 0;

    f32x16 acc;
#pragma unroll
    for (int r = 0; r < 16; ++r) acc[r] = 0.0f;

    __syncthreads();

    if (wid < 2) {
        // ---------------- PRODUCER (wave 0: A tile from pred, wave 1: B from targ) ---------
        const float* src = ((wid == 1) ? targ : pred) + (size_t)batch * NVOX;
        _Float16* T0 = smem + wid * TILE_HALVES;                // buffer 0, my tile
        _Float16* T1 = smem + BUF_HALVES + wid * TILE_HALVES;   // buffer 1, my tile
        int* myp0 = &flg[0 * 2 + wid];
        int* myp1 = &flg[1 * 2 + wid];
        const int c1 = lane, c2 = lane + 64;

        float av = src[(size_t)bx * CHUNK + c1];
        float bv = src[(size_t)bx * CHUNK + c2];
        int kA0 = 0, kB0 = 0, kA1 = 0, kB1 = 0;   // kb_old per (parity, voxel slot)

#define PROD(C, T, MYP, KA, KB, DO_ZERO) { \
        float an = 0.0f, bn = 0.0f; \
        if ((C) + 1 < nchunks) { \
            size_t v = ((size_t)((C) + 1) * BPB + bx) * CHUNK; \
            an = src[v + c1]; bn = src[v + c2]; \
        } \
        if (DO_ZERO) { /* wait consumers done reading chunk C-2 from this buffer */ \
            int e = (C) - 1; \
            while (flg_load(&flg[4 + ((C) & 1) * 2 + 0]) < e) {} \
            while (flg_load(&flg[4 + ((C) & 1) * 2 + 1]) < e) {} \
        } \
        { _Float16 wq[6]; int kb; \
          compute_w(av, kb, wq); \
          if (DO_ZERO) zero6(T, c1, KA); \
          scatter6(T, c1, kb, wq); KA = kb; \
          compute_w(bv, kb, wq); \
          if (DO_ZERO) zero6(T, c2, KB); \
          scatter6(T, c2, kb, wq); KB = kb; } \
        if (lane == 0) flg_store(MYP, (C) + 1); \
        av = an; bv = bn; }

        PROD(0, T0, myp0, kA0, kB0, false)
        PROD(1, T1, myp1, kA1, kB1, false)
#pragma unroll 1
        for (int j = 1; j <= 5; ++j) {
            PROD(2 * j,     T0, myp0, kA0, kB0, true)
            PROD(2 * j + 1, T1, myp1, kA1, kB1, true)
        }
        PROD(12, T0, myp0, kA0, kB0, true)
        if (nchunks == 14) { PROD(13, T1, myp1, kA1, kB1, true) }
#undef PROD
    } else {
        // ---------------- CONSUMER (waves 2,3: K-slice ci*64..+64 of both tiles) ----------
        const int ci = wid - 2;
        const int frag = (1 + (lane & 31)) * STR + ci * 64 + 8 * (lane >> 5);
        int* myc0 = &flg[4 + 0 * 2 + ci];
        int* myc1 = &flg[4 + 1 * 2 + ci];

#define CONS(C, QB, MYC) { \
        int e = (C) + 1; \
        while (flg_load(&flg[(QB) * 2 + 0]) < e) {} \
        while (flg_load(&flg[(QB) * 2 + 1]) < e) {} \
        const _Float16* PA = smem + (QB) * BUF_HALVES; \
        const _Float16* PB = PA + TILE_HALVES; \
        _Pragma("unroll") \
        for (int kk = 0; kk < 4; ++kk) { \
            half8 af = *(const half8*)&PA[frag + kk * 16]; \
            half8 bf = *(const half8*)&PB[frag + kk * 16]; \
            acc = __builtin_amdgcn_mfma_f32_32x32x16_f16(af, bf, acc, 0, 0, 0); \
        } \
        if (lane == 0) flg_store(MYC, e); }

        CONS(0, 0, myc0)
        CONS(1, 1, myc1)
#pragma unroll 1
        for (int j = 1; j <= 5; ++j) {
            CONS(2 * j,     0, myc0)
            CONS(2 * j + 1, 1, myc1)
        }
        CONS(12, 0, myc0)
        if (nchunks == 14) { CONS(13, 1, myc1) }
#undef CONS
    }

    __syncthreads();                             // everyone done; smem reusable

    // epilogue: 2 consumer waves hold K-split partials of the SAME 32x32.
    // C/D layout (32x32): col = lane&31, row = (reg&3) + 8*(reg>>2) + 4*(lane>>5)
    float* red = (float*)smem;                   // 2 * 1024 floats
    if (wid >= 2) {
        const int ci = wid - 2;
        const int colc = lane & 31;
        const int rlo = 4 * (lane >> 5);
#pragma unroll
        for (int r = 0; r < 16; ++r) {
            int rowc = (r & 3) + 8 * (r >> 2) + rlo;
            red[ci * 1024 + rowc * 32 + colc] = acc[r];
        }
    }
    __syncthreads();
    float* H = hist + ((size_t)(bx & (NSLOTS - 1)) * 2 + batch) * 1024;
    for (int idx = tid; idx < 1024; idx += NTHREADS) {
        atomicAdd(&H[idx], red[idx] + red[1024 + idx]);
    }
}

__global__ void mi_reduce_kernel(const float* __restrict__ hist, float* __restrict__ out) {
    __shared__ float s_pab[2 * NBINS * NBINS];
    __shared__ double s_pa[2][NBINS];
    __shared__ double s_pb[2][NBINS];
    __shared__ double s_red[1024];
    const int tid = threadIdx.x;
    const double invN = 1.0 / (double)NVOX;

    for (int g = tid; g < 512; g += 1024) {
        float4 s = make_float4(0.f, 0.f, 0.f, 0.f);
        for (int sl = 0; sl < NSLOTS; ++sl) {
            float4 v = ((const float4*)hist)[sl * 512 + g];
            s.x += v.x; s.y += v.y; s.z += v.z; s.w += v.w;
        }
        ((float4*)s_pab)[g] = s;
    }
    __syncthreads();

    if (tid < 64) {
        int b = tid >> 5, i = tid & 31;
        double s = 0.0;
        for (int j = 0; j < NBINS; ++j) s += (double)s_pab[(b * NBINS + i) * NBINS + j];
        s_pa[b][i] = s * invN;
    } else if (tid < 128) {
        int t2 = tid - 64;
        int b = t2 >> 5, j = t2 & 31;
        double s = 0.0;
        for (int i = 0; i < NBINS; ++i) s += (double)s_pab[(b * NBINS + i) * NBINS + j];
        s_pb[b][j] = s * invN;
    }
    __syncthreads();

    double acc = 0.0;
    for (int idx = tid; idx < 2 * NBINS * NBINS; idx += 1024) {
        int b = idx >> 10;
        int cell = idx & 1023;
        int i = cell >> 5, j = cell & 31;
        double pab = (double)s_pab[idx] * invN;
        double papb = s_pa[b][i] * s_pb[b][j];
        acc += pab * log((pab + 1e-7) / (papb + 1e-7) + 1e-7);
    }
    s_red[tid] = acc;
    __syncthreads();
    for (int s2 = 512; s2 > 0; s2 >>= 1) {
        if (tid < s2) s_red[tid] += s_red[tid + s2];
        __syncthreads();
    }
    if (tid == 0) out[0] = (float)(-0.5 * s_red[0]);
}

extern "C" void kernel_launch(void* const* d_in, const int* in_sizes, int n_in,
                              void* d_out, int out_size, void* d_ws, size_t ws_size,
                              hipStream_t stream) {
    const float* pred = (const float*)d_in[0];
    const float* targ = (const float*)d_in[1];
    float* hist = (float*)d_ws;
    float* out = (float*)d_out;

    hipMemsetAsync(hist, 0, NSLOTS * 2 * NBINS * NBINS * sizeof(float), stream);
    dim3 grid(BPB, 2);
    hipLaunchKernelGGL(mi_hist_kernel, grid, dim3(NTHREADS), 0, stream, pred, targ, hist);
    hipLaunchKernelGGL(mi_reduce_kernel, dim3(1), dim3(1024), 0, stream, hist, out);
}